// Round 2
// baseline (30210.721 us; speedup 1.0000x reference)
//
#include <hip/hip_runtime.h>

#define S_LEN 50
#define T_LEN 50
#define BATCH 128
#define EMB 300
#define ENC_H 512
#define DEC_H 1024
#define TRG_V 23262
#define DEC_IN (DEC_H + EMB)      // 1324
#define KCAT (DEC_IN + DEC_H)     // 2348

static inline int cdiv(int a, int b) { return (a + b - 1) / b; }

__device__ __forceinline__ float sigm(float x) { return 1.f / (1.f + expf(-x)); }

// ---------------- generic GEMM: C = act(A @ W^T + bias + D) ----------------
// A: M x K (row major, lda=K), W: N x K (row major, ldw=K), C: M x N (ldc)
// D (optional): M x N, ld = N.
template<int BM, int BN, int BK, int TM, int TN, int ACT, bool DUAL, bool HAS_BIAS, bool HAS_D>
__global__ __launch_bounds__((BM / TM) * (BN / TN))
void gemm_bt(const float* __restrict__ A, const float* __restrict__ W,
             const float* __restrict__ bias, const float* __restrict__ D,
             float* __restrict__ C, int M, int N, int K, int ldc,
             const float* A1, const float* W1, const float* D1, float* C1)
{
    constexpr int NT  = (BM / TM) * (BN / TN);
    constexpr int NGA = TM / 4;
    constexpr int NGB = TN / 4;
    constexpr int GS  = (BN / TN) * 4;   // column-group spacing
    constexpr int LPA = BM * BK / 4 / NT;
    constexpr int LPB = BN * BK / 4 / NT;

    if (DUAL && blockIdx.z == 1) { A = A1; W = W1; D = D1; C = C1; }

    __shared__ float As[BK][BM + 4];
    __shared__ float Bs[BK][BN + 4];

    const int tid = threadIdx.x;
    const int tx = tid % (BN / TN);
    const int ty = tid / (BN / TN);
    const int m0 = blockIdx.y * BM;
    const int n0 = blockIdx.x * BN;

    float acc[TM][TN];
#pragma unroll
    for (int i = 0; i < TM; i++)
#pragma unroll
        for (int j = 0; j < TN; j++) acc[i][j] = 0.f;

    for (int k0 = 0; k0 < K; k0 += BK) {
#pragma unroll
        for (int e = 0; e < LPA; e++) {
            int idx = tid + e * NT;
            int r = idx / (BK / 4);
            int c4 = idx % (BK / 4);
            int row = m0 + r; if (row > M - 1) row = M - 1;
            int kk = k0 + c4 * 4;
            float4 v;
            if (kk + 3 < K) {
                v = *(const float4*)(A + (size_t)row * K + kk);
            } else {
                v.x = (kk + 0 < K) ? A[(size_t)row * K + kk + 0] : 0.f;
                v.y = (kk + 1 < K) ? A[(size_t)row * K + kk + 1] : 0.f;
                v.z = (kk + 2 < K) ? A[(size_t)row * K + kk + 2] : 0.f;
                v.w = (kk + 3 < K) ? A[(size_t)row * K + kk + 3] : 0.f;
            }
            As[c4 * 4 + 0][r] = v.x; As[c4 * 4 + 1][r] = v.y;
            As[c4 * 4 + 2][r] = v.z; As[c4 * 4 + 3][r] = v.w;
        }
#pragma unroll
        for (int e = 0; e < LPB; e++) {
            int idx = tid + e * NT;
            int r = idx / (BK / 4);
            int c4 = idx % (BK / 4);
            int row = n0 + r; if (row > N - 1) row = N - 1;
            int kk = k0 + c4 * 4;
            float4 v;
            if (kk + 3 < K) {
                v = *(const float4*)(W + (size_t)row * K + kk);
            } else {
                v.x = (kk + 0 < K) ? W[(size_t)row * K + kk + 0] : 0.f;
                v.y = (kk + 1 < K) ? W[(size_t)row * K + kk + 1] : 0.f;
                v.z = (kk + 2 < K) ? W[(size_t)row * K + kk + 2] : 0.f;
                v.w = (kk + 3 < K) ? W[(size_t)row * K + kk + 3] : 0.f;
            }
            Bs[c4 * 4 + 0][r] = v.x; Bs[c4 * 4 + 1][r] = v.y;
            Bs[c4 * 4 + 2][r] = v.z; Bs[c4 * 4 + 3][r] = v.w;
        }
        __syncthreads();
#pragma unroll
        for (int kk = 0; kk < BK; kk++) {
            float a[TM], b[TN];
#pragma unroll
            for (int g = 0; g < NGA; g++) {
                float4 v = *(const float4*)(&As[kk][ty * TM + g * 4]);
                a[g * 4 + 0] = v.x; a[g * 4 + 1] = v.y; a[g * 4 + 2] = v.z; a[g * 4 + 3] = v.w;
            }
#pragma unroll
            for (int g = 0; g < NGB; g++) {
                float4 v = *(const float4*)(&Bs[kk][tx * 4 + g * GS]);
                b[g * 4 + 0] = v.x; b[g * 4 + 1] = v.y; b[g * 4 + 2] = v.z; b[g * 4 + 3] = v.w;
            }
#pragma unroll
            for (int i = 0; i < TM; i++)
#pragma unroll
                for (int j = 0; j < TN; j++)
                    acc[i][j] = fmaf(a[i], b[j], acc[i][j]);
        }
        __syncthreads();
    }

#pragma unroll
    for (int i = 0; i < TM; i++) {
        int row = m0 + ty * TM + i;
        if (row >= M) continue;
#pragma unroll
        for (int g = 0; g < NGB; g++) {
            int colb = n0 + tx * 4 + g * GS;
#pragma unroll
            for (int j = 0; j < 4; j++) {
                int cc = colb + j;
                if (cc >= N) continue;
                float v = acc[i][g * 4 + j];
                if (HAS_BIAS) v += bias[cc];
                if (HAS_D)    v += D[(size_t)row * N + cc];
                if (ACT == 1) v = tanhf(v);
                C[(size_t)row * ldc + cc] = v;
            }
        }
    }
}

// ---------------- small kernels ----------------
__global__ void zero_f32(float* p, size_t n) {
    size_t i = (size_t)blockIdx.x * blockDim.x + threadIdx.x;
    if (i < n) p[i] = 0.f;
}

__global__ void gather_rows(const int* __restrict__ ids, const float* __restrict__ E,
                            float* __restrict__ out, int nrows, int width)
{
    size_t i = (size_t)blockIdx.x * blockDim.x + threadIdx.x;
    size_t total = (size_t)nrows * width;
    if (i >= total) return;
    int r = (int)(i / width);
    int e = (int)(i % width);
    out[i] = E[(size_t)ids[r] * width + e];
}

__global__ void build_wcat(const float* __restrict__ Wih, const float* __restrict__ Whh,
                           float* __restrict__ Wcat)
{
    int i = blockIdx.x * blockDim.x + threadIdx.x;
    if (i >= 4 * DEC_H * KCAT) return;
    int n = i / KCAT, k = i % KCAT;
    Wcat[i] = (k < DEC_IN) ? Wih[(size_t)n * DEC_IN + k] : Whh[(size_t)n * DEC_H + (k - DEC_IN)];
}

// encoder gate fusion for both directions; writes h into enc_out at proper slot
__global__ void enc_gates(const float* __restrict__ gF, const float* __restrict__ gR,
                          float* __restrict__ hF, float* __restrict__ cF,
                          float* __restrict__ hR, float* __restrict__ cR,
                          float* __restrict__ enc_out, int t)
{
    int idx = blockIdx.x * blockDim.x + threadIdx.x;
    if (idx >= 2 * BATCH * ENC_H) return;
    int dir = idx >= BATCH * ENC_H;
    int i = idx - dir * BATCH * ENC_H;
    int b = i / ENC_H, j = i % ENC_H;
    const float* g = dir ? gR : gF;
    float* h = dir ? hR : hF;
    float* c = dir ? cR : cF;
    float gi = g[(size_t)b * 4 * ENC_H + j];
    float gf = g[(size_t)b * 4 * ENC_H + ENC_H + j];
    float gg = g[(size_t)b * 4 * ENC_H + 2 * ENC_H + j];
    float go = g[(size_t)b * 4 * ENC_H + 3 * ENC_H + j];
    float c2 = sigm(gf) * c[i] + sigm(gi) * tanhf(gg);
    float h2 = sigm(go) * tanhf(c2);
    c[i] = c2; h[i] = h2;
    int s_out = dir ? (S_LEN - 1 - t) : t;
    enc_out[((size_t)s_out * BATCH + b) * DEC_H + dir * ENC_H + j] = h2;
}

// decoder init: interleave hF/hR -> hdec, cF/cR -> cdec; seed attn_cat/catA
__global__ void dec_init(const float* __restrict__ hF, const float* __restrict__ cF,
                         const float* __restrict__ hR, const float* __restrict__ cR,
                         const float* __restrict__ trg_emb,
                         float* __restrict__ hdec, float* __restrict__ cdec,
                         float* __restrict__ attn_cat, float* __restrict__ catA)
{
    int idx = blockIdx.x * blockDim.x + threadIdx.x;
    if (idx < BATCH * DEC_H) {
        int b = idx / DEC_H, j = idx % DEC_H;
        int half = j >> 1;
        float h = (j & 1) ? hR[b * ENC_H + half] : hF[b * ENC_H + half];
        float c = (j & 1) ? cR[b * ENC_H + half] : cF[b * ENC_H + half];
        hdec[idx] = h; cdec[idx] = c;
        attn_cat[(size_t)b * 2 * DEC_H + DEC_H + j] = h;
        catA[(size_t)b * KCAT + DEC_IN + j] = h;
    } else {
        int i = idx - BATCH * DEC_H;
        if (i >= BATCH * EMB) return;
        int b = i / EMB, e = i % EMB;
        catA[(size_t)b * KCAT + DEC_H + e] = trg_emb[(size_t)b * EMB + e];  // x_emb for t=0
    }
}

// attention: score->softmax->s_tilde for each batch row (one block per b)
__global__ __launch_bounds__(256)
void attn_kernel(const float* __restrict__ enc_out, const float* __restrict__ semi,
                 float* __restrict__ attn_cat)
{
    int b = blockIdx.x;
    __shared__ float sem[DEC_H];
    __shared__ float sc[S_LEN];
    int tid = threadIdx.x;
    for (int d = tid; d < DEC_H; d += 256) sem[d] = semi[(size_t)b * DEC_H + d];
    __syncthreads();
    int wave = tid >> 6, lane = tid & 63;
    for (int s = wave; s < S_LEN; s += 4) {
        const float* e = enc_out + ((size_t)s * BATCH + b) * DEC_H;
        float p = 0.f;
        for (int d = lane; d < DEC_H; d += 64) p += e[d] * sem[d];
        for (int off = 32; off; off >>= 1) p += __shfl_down(p, off);
        if (lane == 0) sc[s] = p;
    }
    __syncthreads();
    if (tid < 64) {
        float x = (tid < S_LEN) ? sc[tid] : -1e30f;
        float m = x;
        for (int off = 32; off; off >>= 1) m = fmaxf(m, __shfl_xor(m, off));
        float ex = (tid < S_LEN) ? expf(x - m) : 0.f;
        float s = ex;
        for (int off = 32; off; off >>= 1) s += __shfl_xor(s, off);
        if (tid < S_LEN) sc[tid] = ex / s;
    }
    __syncthreads();
    for (int d = tid; d < DEC_H; d += 256) {
        float a = 0.f;
#pragma unroll 5
        for (int s = 0; s < S_LEN; s++)
            a = fmaf(sc[s], enc_out[((size_t)s * BATCH + b) * DEC_H + d], a);
        attn_cat[(size_t)b * 2 * DEC_H + d] = a;
    }
}

// decoder gates; also forwards h into next-step buffers and H_all; copies next x_emb
__global__ void dec_gates(const float* __restrict__ g, const float* __restrict__ trg_emb,
                          float* __restrict__ hdec, float* __restrict__ cdec,
                          float* __restrict__ H_all, float* __restrict__ attn_cat,
                          float* __restrict__ catA, int t)
{
    int idx = blockIdx.x * blockDim.x + threadIdx.x;
    if (idx < BATCH * DEC_H) {
        int b = idx / DEC_H, j = idx % DEC_H;
        float gi = g[(size_t)b * 4 * DEC_H + j];
        float gf = g[(size_t)b * 4 * DEC_H + DEC_H + j];
        float gg = g[(size_t)b * 4 * DEC_H + 2 * DEC_H + j];
        float go = g[(size_t)b * 4 * DEC_H + 3 * DEC_H + j];
        float c2 = sigm(gf) * cdec[idx] + sigm(gi) * tanhf(gg);
        float h2 = sigm(go) * tanhf(c2);
        cdec[idx] = c2; hdec[idx] = h2;
        H_all[(size_t)t * BATCH * DEC_H + idx] = h2;
        attn_cat[(size_t)b * 2 * DEC_H + DEC_H + j] = h2;
        catA[(size_t)b * KCAT + DEC_IN + j] = h2;
    } else {
        int i = idx - BATCH * DEC_H;
        if (i >= BATCH * EMB || t + 1 >= T_LEN - 1) return;
        int b = i / EMB, e = i % EMB;
        catA[(size_t)b * KCAT + DEC_H + e] = trg_emb[((size_t)(t + 1) * BATCH + b) * EMB + e];
    }
}

// in-place row log_softmax
__global__ __launch_bounds__(256)
void log_softmax_rows(float* __restrict__ X, int V)
{
    int row = blockIdx.x;
    float* x = X + (size_t)row * V;
    int tid = threadIdx.x;
    __shared__ float redm[4], reds[4];
    float m = -1e30f;
    for (int i = tid; i < V; i += 256) m = fmaxf(m, x[i]);
    for (int off = 32; off; off >>= 1) m = fmaxf(m, __shfl_xor(m, off));
    if ((tid & 63) == 0) redm[tid >> 6] = m;
    __syncthreads();
    m = fmaxf(fmaxf(redm[0], redm[1]), fmaxf(redm[2], redm[3]));
    float s = 0.f;
    for (int i = tid; i < V; i += 256) s += expf(x[i] - m);
    for (int off = 32; off; off >>= 1) s += __shfl_xor(s, off);
    if ((tid & 63) == 0) reds[tid >> 6] = s;
    __syncthreads();
    s = reds[0] + reds[1] + reds[2] + reds[3];
    float lg = m + logf(s);
    for (int i = tid; i < V; i += 256) x[i] -= lg;
}

// ---------------- launch wrappers ----------------
static void launch_gemm_big_bias(const float* A, const float* W, const float* bias, float* C,
                                 int M, int N, int K, int ldc, hipStream_t s)
{
    dim3 g(cdiv(N, 128), cdiv(M, 128), 1);
    gemm_bt<128, 128, 16, 8, 8, 0, false, true, false><<<g, 256, 0, s>>>(
        A, W, bias, nullptr, C, M, N, K, ldc, nullptr, nullptr, nullptr, nullptr);
}
static void launch_gemm_sk(const float* A, const float* W, float* C,
                           int M, int N, int K, int ldc, hipStream_t s)
{
    dim3 g(cdiv(N, 64), cdiv(M, 64), 1);
    gemm_bt<64, 64, 16, 4, 4, 0, false, false, false><<<g, 256, 0, s>>>(
        A, W, nullptr, nullptr, C, M, N, K, ldc, nullptr, nullptr, nullptr, nullptr);
}
static void launch_gemm_sk_tanh(const float* A, const float* W, float* C,
                                int M, int N, int K, int ldc, hipStream_t s)
{
    dim3 g(cdiv(N, 64), cdiv(M, 64), 1);
    gemm_bt<64, 64, 16, 4, 4, 1, false, false, false><<<g, 256, 0, s>>>(
        A, W, nullptr, nullptr, C, M, N, K, ldc, nullptr, nullptr, nullptr, nullptr);
}
static void launch_gemm_sk_bias(const float* A, const float* W, const float* bias, float* C,
                                int M, int N, int K, int ldc, hipStream_t s)
{
    dim3 g(cdiv(N, 64), cdiv(M, 64), 1);
    gemm_bt<64, 64, 16, 4, 4, 0, false, true, false><<<g, 256, 0, s>>>(
        A, W, bias, nullptr, C, M, N, K, ldc, nullptr, nullptr, nullptr, nullptr);
}
static void launch_gemm_dual(const float* A0, const float* W0, const float* D0, float* C0,
                             const float* A1, const float* W1, const float* D1, float* C1,
                             int M, int N, int K, int ldc, hipStream_t s)
{
    dim3 g(cdiv(N, 64), cdiv(M, 64), 2);
    gemm_bt<64, 64, 16, 4, 4, 0, true, false, true><<<g, 256, 0, s>>>(
        A0, W0, nullptr, D0, C0, M, N, K, ldc, A1, W1, D1, C1);
}

extern "C" void kernel_launch(void* const* d_in, const int* in_sizes, int n_in,
                              void* d_out, int out_size, void* d_ws, size_t ws_size,
                              hipStream_t stream)
{
    const int*   src   = (const int*)d_in[0];
    const int*   trg   = (const int*)d_in[1];
    const float* EEMBp = (const float*)d_in[2];
    const float* eWihF = (const float*)d_in[3];
    const float* eWhhF = (const float*)d_in[4];
    const float* ebF   = (const float*)d_in[5];
    const float* eWihR = (const float*)d_in[6];
    const float* eWhhR = (const float*)d_in[7];
    const float* ebR   = (const float*)d_in[8];
    const float* aWi   = (const float*)d_in[9];
    const float* aWo   = (const float*)d_in[10];
    const float* dWih  = (const float*)d_in[11];
    const float* dWhh  = (const float*)d_in[12];
    const float* db    = (const float*)d_in[13];
    const float* DEMBp = (const float*)d_in[14];
    const float* gW    = (const float*)d_in[15];
    const float* gb    = (const float*)d_in[16];
    float* out = (float*)d_out;
    float* ws  = (float*)d_ws;

    size_t off = 0;
    auto alloc = [&](size_t n) { float* p = ws + off; off += n; return p; };

    float* Gf      = alloc((size_t)S_LEN * BATCH * 4 * ENC_H);   // 13107200
    float* Gr      = alloc((size_t)S_LEN * BATCH * 4 * ENC_H);
    float* emb_src = alloc((size_t)S_LEN * BATCH * EMB);
    float* enc_out = alloc((size_t)S_LEN * BATCH * DEC_H);
    float* hF      = alloc(BATCH * ENC_H);
    float* cF      = alloc(BATCH * ENC_H);
    float* hR      = alloc(BATCH * ENC_H);
    float* cR      = alloc(BATCH * ENC_H);
    float* gEncF   = alloc(BATCH * 4 * ENC_H);
    float* gEncR   = alloc(BATCH * 4 * ENC_H);
    float* trg_emb = alloc((size_t)(T_LEN - 1) * BATCH * EMB);
    float* Wcat    = alloc((size_t)4 * DEC_H * KCAT);            // 9617408
    float* hdec    = alloc(BATCH * DEC_H);
    float* cdec    = alloc(BATCH * DEC_H);
    float* semi    = alloc(BATCH * DEC_H);
    float* attn_cat= alloc((size_t)BATCH * 2 * DEC_H);
    float* catA    = alloc((size_t)BATCH * KCAT);
    float* gDec    = alloc((size_t)BATCH * 4 * DEC_H);
    float* H_all   = alloc((size_t)(T_LEN - 1) * BATCH * DEC_H);

    // ---- init zeros: first output slice + encoder h/c (contiguous hF..cR) ----
    {
        size_t n = (size_t)BATCH * TRG_V;
        zero_f32<<<cdiv((int)n, 256), 256, 0, stream>>>(out, n);
        zero_f32<<<cdiv(4 * BATCH * ENC_H, 256), 256, 0, stream>>>(hF, (size_t)4 * BATCH * ENC_H);
    }

    // ---- embeddings ----
    gather_rows<<<cdiv(S_LEN * BATCH * EMB, 256), 256, 0, stream>>>(src, EEMBp, emb_src, S_LEN * BATCH, EMB);
    gather_rows<<<cdiv((T_LEN - 1) * BATCH * EMB, 256), 256, 0, stream>>>(trg, DEMBp, trg_emb, (T_LEN - 1) * BATCH, EMB);

    // ---- concat decoder weights ----
    build_wcat<<<cdiv(4 * DEC_H * KCAT, 256), 256, 0, stream>>>(dWih, dWhh, Wcat);

    // ---- encoder input GEMMs (bias folded in) ----
    launch_gemm_big_bias(emb_src, eWihF, ebF, Gf, S_LEN * BATCH, 4 * ENC_H, EMB, 4 * ENC_H, stream);
    launch_gemm_big_bias(emb_src, eWihR, ebR, Gr, S_LEN * BATCH, 4 * ENC_H, EMB, 4 * ENC_H, stream);

    // ---- encoder recurrence (both directions per launch) ----
    for (int t = 0; t < S_LEN; t++) {
        const float* Df = Gf + (size_t)t * BATCH * 4 * ENC_H;
        const float* Dr = Gr + (size_t)(S_LEN - 1 - t) * BATCH * 4 * ENC_H;
        launch_gemm_dual(hF, eWhhF, Df, gEncF, hR, eWhhR, Dr, gEncR,
                         BATCH, 4 * ENC_H, ENC_H, 4 * ENC_H, stream);
        enc_gates<<<cdiv(2 * BATCH * ENC_H, 256), 256, 0, stream>>>(gEncF, gEncR, hF, cF, hR, cR, enc_out, t);
    }

    // ---- decoder init ----
    dec_init<<<cdiv(BATCH * DEC_H + BATCH * EMB, 256), 256, 0, stream>>>(
        hF, cF, hR, cR, trg_emb, hdec, cdec, attn_cat, catA);

    // ---- decoder recurrence ----
    for (int t = 0; t < T_LEN - 1; t++) {
        launch_gemm_sk(hdec, aWi, semi, BATCH, DEC_H, DEC_H, DEC_H, stream);
        attn_kernel<<<BATCH, 256, 0, stream>>>(enc_out, semi, attn_cat);
        launch_gemm_sk_tanh(attn_cat, aWo, catA, BATCH, DEC_H, 2 * DEC_H, KCAT, stream);
        launch_gemm_sk_bias(catA, Wcat, db, gDec, BATCH, 4 * DEC_H, KCAT, 4 * DEC_H, stream);
        dec_gates<<<cdiv(BATCH * DEC_H + BATCH * EMB, 256), 256, 0, stream>>>(
            gDec, trg_emb, hdec, cdec, H_all, attn_cat, catA, t);
    }

    // ---- generator: logits for all 49 steps at once, into d_out rows 128.. ----
    launch_gemm_big_bias(H_all, gW, gb, out + (size_t)BATCH * TRG_V,
                         (T_LEN - 1) * BATCH, TRG_V, DEC_H, TRG_V, stream);

    // ---- in-place log_softmax over vocab ----
    log_softmax_rows<<<(T_LEN - 1) * BATCH, 256, 0, stream>>>(out + (size_t)BATCH * TRG_V, TRG_V);
}

// Round 4
// 26616.678 us; speedup vs baseline: 1.1350x; 1.1350x over previous
//
#include <hip/hip_runtime.h>
#include <hip/hip_bf16.h>

#define S_LEN 50
#define T_LEN 50
#define BATCH 128
#define EMB 300
#define ENC_H 512
#define DEC_H 1024
#define TRG_V 23262
#define DEC_IN (DEC_H + EMB)      // 1324
#define KCAT (DEC_IN + DEC_H)     // 2348

static inline int cdiv(int a, int b) { return (a + b - 1) / b; }

__device__ __forceinline__ float sigm(float x) { return 1.f / (1.f + expf(-x)); }

typedef __attribute__((ext_vector_type(8))) short bf16x8;
typedef __attribute__((ext_vector_type(4))) float f32x4;

__device__ __forceinline__ void gload_lds16(const void* g, void* l) {
    __builtin_amdgcn_global_load_lds((const __attribute__((address_space(1))) int*)g,
                                     (__attribute__((address_space(3))) int*)l, 16, 0, 0);
}

// ---------------- MFMA bf16 GEMM: C = A @ W^T + bias ----------------
// A: M x K bf16 row-major (M % 128 == 0, K % 32 == 0)
// W: N x K bf16 row-major (N arbitrary; rows clamped)
// C: M x N fp32, ldc
__global__ __launch_bounds__(256)
void gemm_mfma_bf16(const __hip_bfloat16* __restrict__ A, const __hip_bfloat16* __restrict__ W,
                    const float* __restrict__ bias, float* __restrict__ C,
                    int M, int N, int K, int ldc)
{
    __shared__ short As[128 * 32];
    __shared__ short Bs[128 * 32];
    const int tid  = threadIdx.x;
    const int wave = tid >> 6;
    const int lane = tid & 63;
    const int m0 = blockIdx.y * 128;
    const int n0 = blockIdx.x * 128;
    const int wr = wave >> 1, wc = wave & 1;

    const int srow = lane >> 2;   // 0..15 within 16-row staging slab
    const int kgrp = lane & 3;    // 0..3 (8 bf16 each)
    const int arow0 = 32 * wave;  // wave's 32-row slab

    f32x4 acc[4][4] = {};

    for (int k0 = 0; k0 < K; k0 += 32) {
#pragma unroll
        for (int c = 0; c < 2; c++) {
            int row = arow0 + 16 * c + srow;
            gload_lds16(A + (size_t)(m0 + row) * K + k0 + kgrp * 8,
                        &As[(arow0 + 16 * c) * 32]);
        }
#pragma unroll
        for (int c = 0; c < 2; c++) {
            int row = arow0 + 16 * c + srow;
            int gr = n0 + row; if (gr > N - 1) gr = N - 1;
            gload_lds16(W + (size_t)gr * K + k0 + kgrp * 8,
                        &Bs[(arow0 + 16 * c) * 32]);
        }
        __syncthreads();

        bf16x8 a[4], b[4];
#pragma unroll
        for (int mi = 0; mi < 4; mi++)
            a[mi] = *(const bf16x8*)&As[(wr * 64 + mi * 16 + (lane & 15)) * 32 + (lane >> 4) * 8];
#pragma unroll
        for (int ni = 0; ni < 4; ni++)
            b[ni] = *(const bf16x8*)&Bs[(wc * 64 + ni * 16 + (lane & 15)) * 32 + (lane >> 4) * 8];
#pragma unroll
        for (int mi = 0; mi < 4; mi++)
#pragma unroll
            for (int ni = 0; ni < 4; ni++)
                acc[mi][ni] = __builtin_amdgcn_mfma_f32_16x16x32_bf16(a[mi], b[ni], acc[mi][ni], 0, 0, 0);
        __syncthreads();
    }

#pragma unroll
    for (int mi = 0; mi < 4; mi++)
#pragma unroll
        for (int ni = 0; ni < 4; ni++) {
            int col = n0 + wc * 64 + ni * 16 + (lane & 15);
            if (col >= N) continue;
            float bv = bias[col];
#pragma unroll
            for (int r = 0; r < 4; r++) {
                int row = m0 + wr * 64 + mi * 16 + (lane >> 4) * 4 + r;
                C[(size_t)row * ldc + col] = acc[mi][ni][r] + bv;
            }
        }
}

__global__ void cast_f32_bf16(const float* __restrict__ in, __hip_bfloat16* __restrict__ out, size_t n)
{
    size_t i = ((size_t)blockIdx.x * blockDim.x + threadIdx.x) * 4;
    if (i + 3 < n) {
        float4 v = *(const float4*)(in + i);
        out[i + 0] = __float2bfloat16(v.x);
        out[i + 1] = __float2bfloat16(v.y);
        out[i + 2] = __float2bfloat16(v.z);
        out[i + 3] = __float2bfloat16(v.w);
    } else {
        for (; i < n; i++) out[i] = __float2bfloat16(in[i]);
    }
}

// ---------------- generic fp32 GEMM: C = act(A @ W^T + bias + D) ----------------
template<int BM, int BN, int BK, int TM, int TN, int ACT, bool DUAL, bool HAS_BIAS, bool HAS_D>
__global__ __launch_bounds__((BM / TM) * (BN / TN))
void gemm_bt(const float* __restrict__ A, const float* __restrict__ W,
             const float* __restrict__ bias, const float* __restrict__ D,
             float* __restrict__ C, int M, int N, int K, int ldc,
             const float* A1, const float* W1, const float* D1, float* C1)
{
    constexpr int NT  = (BM / TM) * (BN / TN);
    constexpr int NGA = TM / 4;
    constexpr int NGB = TN / 4;
    constexpr int GS  = (BN / TN) * 4;
    constexpr int LPA = BM * BK / 4 / NT;
    constexpr int LPB = BN * BK / 4 / NT;

    if (DUAL && blockIdx.z == 1) { A = A1; W = W1; D = D1; C = C1; }

    __shared__ float As[BK][BM + 4];
    __shared__ float Bs[BK][BN + 4];

    const int tid = threadIdx.x;
    const int tx = tid % (BN / TN);
    const int ty = tid / (BN / TN);
    const int m0 = blockIdx.y * BM;
    const int n0 = blockIdx.x * BN;

    float acc[TM][TN];
#pragma unroll
    for (int i = 0; i < TM; i++)
#pragma unroll
        for (int j = 0; j < TN; j++) acc[i][j] = 0.f;

    for (int k0 = 0; k0 < K; k0 += BK) {
#pragma unroll
        for (int e = 0; e < LPA; e++) {
            int idx = tid + e * NT;
            int r = idx / (BK / 4);
            int c4 = idx % (BK / 4);
            int row = m0 + r; if (row > M - 1) row = M - 1;
            int kk = k0 + c4 * 4;
            float4 v;
            if (kk + 3 < K) {
                v = *(const float4*)(A + (size_t)row * K + kk);
            } else {
                v.x = (kk + 0 < K) ? A[(size_t)row * K + kk + 0] : 0.f;
                v.y = (kk + 1 < K) ? A[(size_t)row * K + kk + 1] : 0.f;
                v.z = (kk + 2 < K) ? A[(size_t)row * K + kk + 2] : 0.f;
                v.w = (kk + 3 < K) ? A[(size_t)row * K + kk + 3] : 0.f;
            }
            As[c4 * 4 + 0][r] = v.x; As[c4 * 4 + 1][r] = v.y;
            As[c4 * 4 + 2][r] = v.z; As[c4 * 4 + 3][r] = v.w;
        }
#pragma unroll
        for (int e = 0; e < LPB; e++) {
            int idx = tid + e * NT;
            int r = idx / (BK / 4);
            int c4 = idx % (BK / 4);
            int row = n0 + r; if (row > N - 1) row = N - 1;
            int kk = k0 + c4 * 4;
            float4 v;
            if (kk + 3 < K) {
                v = *(const float4*)(W + (size_t)row * K + kk);
            } else {
                v.x = (kk + 0 < K) ? W[(size_t)row * K + kk + 0] : 0.f;
                v.y = (kk + 1 < K) ? W[(size_t)row * K + kk + 1] : 0.f;
                v.z = (kk + 2 < K) ? W[(size_t)row * K + kk + 2] : 0.f;
                v.w = (kk + 3 < K) ? W[(size_t)row * K + kk + 3] : 0.f;
            }
            Bs[c4 * 4 + 0][r] = v.x; Bs[c4 * 4 + 1][r] = v.y;
            Bs[c4 * 4 + 2][r] = v.z; Bs[c4 * 4 + 3][r] = v.w;
        }
        __syncthreads();
#pragma unroll
        for (int kk = 0; kk < BK; kk++) {
            float a[TM], b[TN];
#pragma unroll
            for (int g = 0; g < NGA; g++) {
                float4 v = *(const float4*)(&As[kk][ty * TM + g * 4]);
                a[g * 4 + 0] = v.x; a[g * 4 + 1] = v.y; a[g * 4 + 2] = v.z; a[g * 4 + 3] = v.w;
            }
#pragma unroll
            for (int g = 0; g < NGB; g++) {
                float4 v = *(const float4*)(&Bs[kk][tx * 4 + g * GS]);
                b[g * 4 + 0] = v.x; b[g * 4 + 1] = v.y; b[g * 4 + 2] = v.z; b[g * 4 + 3] = v.w;
            }
#pragma unroll
            for (int i = 0; i < TM; i++)
#pragma unroll
                for (int j = 0; j < TN; j++)
                    acc[i][j] = fmaf(a[i], b[j], acc[i][j]);
        }
        __syncthreads();
    }

#pragma unroll
    for (int i = 0; i < TM; i++) {
        int row = m0 + ty * TM + i;
        if (row >= M) continue;
#pragma unroll
        for (int g = 0; g < NGB; g++) {
            int colb = n0 + tx * 4 + g * GS;
#pragma unroll
            for (int j = 0; j < 4; j++) {
                int cc = colb + j;
                if (cc >= N) continue;
                float v = acc[i][g * 4 + j];
                if (HAS_BIAS) v += bias[cc];
                if (HAS_D)    v += D[(size_t)row * N + cc];
                if (ACT == 1) v = tanhf(v);
                C[(size_t)row * ldc + cc] = v;
            }
        }
    }
}

// ---------------- small kernels ----------------
__global__ void zero_f32(float* p, size_t n) {
    size_t i = (size_t)blockIdx.x * blockDim.x + threadIdx.x;
    if (i < n) p[i] = 0.f;
}

__global__ void gather_rows(const int* __restrict__ ids, const float* __restrict__ E,
                            float* __restrict__ out, int nrows, int width)
{
    size_t i = (size_t)blockIdx.x * blockDim.x + threadIdx.x;
    size_t total = (size_t)nrows * width;
    if (i >= total) return;
    int r = (int)(i / width);
    int e = (int)(i % width);
    out[i] = E[(size_t)ids[r] * width + e];
}

__global__ void build_wcat(const float* __restrict__ Wih, const float* __restrict__ Whh,
                           float* __restrict__ Wcat)
{
    int i = blockIdx.x * blockDim.x + threadIdx.x;
    if (i >= 4 * DEC_H * KCAT) return;
    int n = i / KCAT, k = i % KCAT;
    Wcat[i] = (k < DEC_IN) ? Wih[(size_t)n * DEC_IN + k] : Whh[(size_t)n * DEC_H + (k - DEC_IN)];
}

__global__ void enc_gates(const float* __restrict__ gF, const float* __restrict__ gR,
                          float* __restrict__ hF, float* __restrict__ cF,
                          float* __restrict__ hR, float* __restrict__ cR,
                          float* __restrict__ enc_out, int t)
{
    int idx = blockIdx.x * blockDim.x + threadIdx.x;
    if (idx >= 2 * BATCH * ENC_H) return;
    int dir = idx >= BATCH * ENC_H;
    int i = idx - dir * BATCH * ENC_H;
    int b = i / ENC_H, j = i % ENC_H;
    const float* g = dir ? gR : gF;
    float* h = dir ? hR : hF;
    float* c = dir ? cR : cF;
    float gi = g[(size_t)b * 4 * ENC_H + j];
    float gf = g[(size_t)b * 4 * ENC_H + ENC_H + j];
    float gg = g[(size_t)b * 4 * ENC_H + 2 * ENC_H + j];
    float go = g[(size_t)b * 4 * ENC_H + 3 * ENC_H + j];
    float c2 = sigm(gf) * c[i] + sigm(gi) * tanhf(gg);
    float h2 = sigm(go) * tanhf(c2);
    c[i] = c2; h[i] = h2;
    int s_out = dir ? (S_LEN - 1 - t) : t;
    enc_out[((size_t)s_out * BATCH + b) * DEC_H + dir * ENC_H + j] = h2;
}

__global__ void dec_init(const float* __restrict__ hF, const float* __restrict__ cF,
                         const float* __restrict__ hR, const float* __restrict__ cR,
                         const float* __restrict__ trg_emb,
                         float* __restrict__ hdec, float* __restrict__ cdec,
                         float* __restrict__ attn_cat, float* __restrict__ catA)
{
    int idx = blockIdx.x * blockDim.x + threadIdx.x;
    if (idx < BATCH * DEC_H) {
        int b = idx / DEC_H, j = idx % DEC_H;
        int half = j >> 1;
        float h = (j & 1) ? hR[b * ENC_H + half] : hF[b * ENC_H + half];
        float c = (j & 1) ? cR[b * ENC_H + half] : cF[b * ENC_H + half];
        hdec[idx] = h; cdec[idx] = c;
        attn_cat[(size_t)b * 2 * DEC_H + DEC_H + j] = h;
        catA[(size_t)b * KCAT + DEC_IN + j] = h;
    } else {
        int i = idx - BATCH * DEC_H;
        if (i >= BATCH * EMB) return;
        int b = i / EMB, e = i % EMB;
        catA[(size_t)b * KCAT + DEC_H + e] = trg_emb[(size_t)b * EMB + e];
    }
}

__global__ __launch_bounds__(256)
void attn_kernel(const float* __restrict__ enc_out, const float* __restrict__ semi,
                 float* __restrict__ attn_cat)
{
    int b = blockIdx.x;
    __shared__ float sem[DEC_H];
    __shared__ float sc[S_LEN];
    int tid = threadIdx.x;
    for (int d = tid; d < DEC_H; d += 256) sem[d] = semi[(size_t)b * DEC_H + d];
    __syncthreads();
    int wave = tid >> 6, lane = tid & 63;
    for (int s = wave; s < S_LEN; s += 4) {
        const float* e = enc_out + ((size_t)s * BATCH + b) * DEC_H;
        float p = 0.f;
        for (int d = lane; d < DEC_H; d += 64) p += e[d] * sem[d];
        for (int off = 32; off; off >>= 1) p += __shfl_down(p, off);
        if (lane == 0) sc[s] = p;
    }
    __syncthreads();
    if (tid < 64) {
        float x = (tid < S_LEN) ? sc[tid] : -1e30f;
        float m = x;
        for (int off = 32; off; off >>= 1) m = fmaxf(m, __shfl_xor(m, off));
        float ex = (tid < S_LEN) ? expf(x - m) : 0.f;
        float s = ex;
        for (int off = 32; off; off >>= 1) s += __shfl_xor(s, off);
        if (tid < S_LEN) sc[tid] = ex / s;
    }
    __syncthreads();
    for (int d = tid; d < DEC_H; d += 256) {
        float a = 0.f;
#pragma unroll 5
        for (int s = 0; s < S_LEN; s++)
            a = fmaf(sc[s], enc_out[((size_t)s * BATCH + b) * DEC_H + d], a);
        attn_cat[(size_t)b * 2 * DEC_H + d] = a;
    }
}

// decoder gates; writes h as bf16 into H_bf for the MFMA generator GEMM
__global__ void dec_gates(const float* __restrict__ g, const float* __restrict__ trg_emb,
                          float* __restrict__ hdec, float* __restrict__ cdec,
                          __hip_bfloat16* __restrict__ H_bf, float* __restrict__ attn_cat,
                          float* __restrict__ catA, int t)
{
    int idx = blockIdx.x * blockDim.x + threadIdx.x;
    if (idx < BATCH * DEC_H) {
        int b = idx / DEC_H, j = idx % DEC_H;
        float gi = g[(size_t)b * 4 * DEC_H + j];
        float gf = g[(size_t)b * 4 * DEC_H + DEC_H + j];
        float gg = g[(size_t)b * 4 * DEC_H + 2 * DEC_H + j];
        float go = g[(size_t)b * 4 * DEC_H + 3 * DEC_H + j];
        float c2 = sigm(gf) * cdec[idx] + sigm(gi) * tanhf(gg);
        float h2 = sigm(go) * tanhf(c2);
        cdec[idx] = c2; hdec[idx] = h2;
        H_bf[(size_t)t * BATCH * DEC_H + idx] = __float2bfloat16(h2);
        attn_cat[(size_t)b * 2 * DEC_H + DEC_H + j] = h2;
        catA[(size_t)b * KCAT + DEC_IN + j] = h2;
    } else {
        int i = idx - BATCH * DEC_H;
        if (i >= BATCH * EMB || t + 1 >= T_LEN - 1) return;
        int b = i / EMB, e = i % EMB;
        catA[(size_t)b * KCAT + DEC_H + e] = trg_emb[((size_t)(t + 1) * BATCH + b) * EMB + e];
    }
}

__global__ __launch_bounds__(256)
void log_softmax_rows(float* __restrict__ X, int V)
{
    int row = blockIdx.x;
    float* x = X + (size_t)row * V;
    int tid = threadIdx.x;
    __shared__ float redm[4], reds[4];
    float m = -1e30f;
    for (int i = tid; i < V; i += 256) m = fmaxf(m, x[i]);
    for (int off = 32; off; off >>= 1) m = fmaxf(m, __shfl_xor(m, off));
    if ((tid & 63) == 0) redm[tid >> 6] = m;
    __syncthreads();
    m = fmaxf(fmaxf(redm[0], redm[1]), fmaxf(redm[2], redm[3]));
    float s = 0.f;
    for (int i = tid; i < V; i += 256) s += expf(x[i] - m);
    for (int off = 32; off; off >>= 1) s += __shfl_xor(s, off);
    if ((tid & 63) == 0) reds[tid >> 6] = s;
    __syncthreads();
    s = reds[0] + reds[1] + reds[2] + reds[3];
    float lg = m + logf(s);
    for (int i = tid; i < V; i += 256) x[i] -= lg;
}

// ---------------- launch wrappers ----------------
static void launch_gemm_big_bias(const float* A, const float* W, const float* bias, float* C,
                                 int M, int N, int K, int ldc, hipStream_t s)
{
    dim3 g(cdiv(N, 128), cdiv(M, 128), 1);
    gemm_bt<128, 128, 16, 8, 8, 0, false, true, false><<<g, 256, 0, s>>>(
        A, W, bias, nullptr, C, M, N, K, ldc, nullptr, nullptr, nullptr, nullptr);
}
static void launch_gemm_sk(const float* A, const float* W, float* C,
                           int M, int N, int K, int ldc, hipStream_t s)
{
    dim3 g(cdiv(N, 64), cdiv(M, 64), 1);
    gemm_bt<64, 64, 16, 4, 4, 0, false, false, false><<<g, 256, 0, s>>>(
        A, W, nullptr, nullptr, C, M, N, K, ldc, nullptr, nullptr, nullptr, nullptr);
}
static void launch_gemm_sk_tanh(const float* A, const float* W, float* C,
                                int M, int N, int K, int ldc, hipStream_t s)
{
    dim3 g(cdiv(N, 64), cdiv(M, 64), 1);
    gemm_bt<64, 64, 16, 4, 4, 1, false, false, false><<<g, 256, 0, s>>>(
        A, W, nullptr, nullptr, C, M, N, K, ldc, nullptr, nullptr, nullptr, nullptr);
}
static void launch_gemm_sk_bias(const float* A, const float* W, const float* bias, float* C,
                                int M, int N, int K, int ldc, hipStream_t s)
{
    dim3 g(cdiv(N, 64), cdiv(M, 64), 1);
    gemm_bt<64, 64, 16, 4, 4, 0, false, true, false><<<g, 256, 0, s>>>(
        A, W, bias, nullptr, C, M, N, K, ldc, nullptr, nullptr, nullptr, nullptr);
}
static void launch_gemm_dual(const float* A0, const float* W0, const float* D0, float* C0,
                             const float* A1, const float* W1, const float* D1, float* C1,
                             int M, int N, int K, int ldc, hipStream_t s)
{
    dim3 g(cdiv(N, 64), cdiv(M, 64), 2);
    gemm_bt<64, 64, 16, 4, 4, 0, true, false, true><<<g, 256, 0, s>>>(
        A0, W0, nullptr, D0, C0, M, N, K, ldc, A1, W1, D1, C1);
}

extern "C" void kernel_launch(void* const* d_in, const int* in_sizes, int n_in,
                              void* d_out, int out_size, void* d_ws, size_t ws_size,
                              hipStream_t stream)
{
    const int*   src   = (const int*)d_in[0];
    const int*   trg   = (const int*)d_in[1];
    const float* EEMBp = (const float*)d_in[2];
    const float* eWihF = (const float*)d_in[3];
    const float* eWhhF = (const float*)d_in[4];
    const float* ebF   = (const float*)d_in[5];
    const float* eWihR = (const float*)d_in[6];
    const float* eWhhR = (const float*)d_in[7];
    const float* ebR   = (const float*)d_in[8];
    const float* aWi   = (const float*)d_in[9];
    const float* aWo   = (const float*)d_in[10];
    const float* dWih  = (const float*)d_in[11];
    const float* dWhh  = (const float*)d_in[12];
    const float* db    = (const float*)d_in[13];
    const float* DEMBp = (const float*)d_in[14];
    const float* gW    = (const float*)d_in[15];
    const float* gb    = (const float*)d_in[16];
    float* out = (float*)d_out;
    float* ws  = (float*)d_ws;

    size_t off = 0;
    auto alloc = [&](size_t n) { float* p = ws + off; off += n; return p; };

    float* Gf      = alloc((size_t)S_LEN * BATCH * 4 * ENC_H);   // dead after encoder loop
    float* Gr      = alloc((size_t)S_LEN * BATCH * 4 * ENC_H);
    float* emb_src = alloc((size_t)S_LEN * BATCH * EMB);
    float* enc_out = alloc((size_t)S_LEN * BATCH * DEC_H);
    float* hF      = alloc(BATCH * ENC_H);
    float* cF      = alloc(BATCH * ENC_H);
    float* hR      = alloc(BATCH * ENC_H);
    float* cR      = alloc(BATCH * ENC_H);
    float* gEncF   = alloc(BATCH * 4 * ENC_H);
    float* gEncR   = alloc(BATCH * 4 * ENC_H);
    float* trg_emb = alloc((size_t)(T_LEN - 1) * BATCH * EMB);
    float* Wcat    = alloc((size_t)4 * DEC_H * KCAT);
    float* hdec    = alloc(BATCH * DEC_H);
    float* cdec    = alloc(BATCH * DEC_H);
    float* semi    = alloc(BATCH * DEC_H);
    float* attn_cat= alloc((size_t)BATCH * 2 * DEC_H);
    float* catA    = alloc((size_t)BATCH * KCAT);
    float* gDec    = alloc((size_t)BATCH * 4 * DEC_H);
    __hip_bfloat16* H_bf = (__hip_bfloat16*)alloc((size_t)(T_LEN - 1) * BATCH * DEC_H / 2);
    // gWb aliases Gf: Gf (13.1M floats) is dead after the encoder recurrence;
    // gWb needs 23262*1024 bf16 = 11.9M float-equivalents. Cast launched after
    // the encoder loop, consumed only by the final generator GEMM.
    __hip_bfloat16* gWb = (__hip_bfloat16*)Gf;

    // ---- init zeros: first output slice + encoder h/c (contiguous hF..cR) ----
    {
        size_t n = (size_t)BATCH * TRG_V;
        zero_f32<<<cdiv((int)n, 256), 256, 0, stream>>>(out, n);
        zero_f32<<<cdiv(4 * BATCH * ENC_H, 256), 256, 0, stream>>>(hF, (size_t)4 * BATCH * ENC_H);
    }

    // ---- embeddings ----
    gather_rows<<<cdiv(S_LEN * BATCH * EMB, 256), 256, 0, stream>>>(src, EEMBp, emb_src, S_LEN * BATCH, EMB);
    gather_rows<<<cdiv((T_LEN - 1) * BATCH * EMB, 256), 256, 0, stream>>>(trg, DEMBp, trg_emb, (T_LEN - 1) * BATCH, EMB);

    // ---- concat decoder weights ----
    build_wcat<<<cdiv(4 * DEC_H * KCAT, 256), 256, 0, stream>>>(dWih, dWhh, Wcat);

    // ---- encoder input GEMMs (bias folded in) ----
    launch_gemm_big_bias(emb_src, eWihF, ebF, Gf, S_LEN * BATCH, 4 * ENC_H, EMB, 4 * ENC_H, stream);
    launch_gemm_big_bias(emb_src, eWihR, ebR, Gr, S_LEN * BATCH, 4 * ENC_H, EMB, 4 * ENC_H, stream);

    // ---- encoder recurrence ----
    for (int t = 0; t < S_LEN; t++) {
        const float* Df = Gf + (size_t)t * BATCH * 4 * ENC_H;
        const float* Dr = Gr + (size_t)(S_LEN - 1 - t) * BATCH * 4 * ENC_H;
        launch_gemm_dual(hF, eWhhF, Df, gEncF, hR, eWhhR, Dr, gEncR,
                         BATCH, 4 * ENC_H, ENC_H, 4 * ENC_H, stream);
        enc_gates<<<cdiv(2 * BATCH * ENC_H, 256), 256, 0, stream>>>(gEncF, gEncR, hF, cF, hR, cR, enc_out, t);
    }

    // ---- cast generator weights to bf16 into Gf's (now dead) space ----
    {
        size_t n = (size_t)TRG_V * DEC_H;
        cast_f32_bf16<<<cdiv((int)(n / 4), 256), 256, 0, stream>>>(gW, gWb, n);
    }

    // ---- decoder init ----
    dec_init<<<cdiv(BATCH * DEC_H + BATCH * EMB, 256), 256, 0, stream>>>(
        hF, cF, hR, cR, trg_emb, hdec, cdec, attn_cat, catA);

    // ---- decoder recurrence ----
    for (int t = 0; t < T_LEN - 1; t++) {
        launch_gemm_sk(hdec, aWi, semi, BATCH, DEC_H, DEC_H, DEC_H, stream);
        attn_kernel<<<BATCH, 256, 0, stream>>>(enc_out, semi, attn_cat);
        launch_gemm_sk_tanh(attn_cat, aWo, catA, BATCH, DEC_H, 2 * DEC_H, KCAT, stream);
        launch_gemm_sk_bias(catA, Wcat, db, gDec, BATCH, 4 * DEC_H, KCAT, 4 * DEC_H, stream);
        dec_gates<<<cdiv(BATCH * DEC_H + BATCH * EMB, 256), 256, 0, stream>>>(
            gDec, trg_emb, hdec, cdec, H_bf, attn_cat, catA, t);
    }

    // ---- generator: MFMA bf16 GEMM, logits for all 49 steps into d_out rows 128.. ----
    {
        dim3 g(cdiv(TRG_V, 128), cdiv((T_LEN - 1) * BATCH, 128), 1);
        gemm_mfma_bf16<<<g, 256, 0, stream>>>(H_bf, gWb, gb, out + (size_t)BATCH * TRG_V,
                                              (T_LEN - 1) * BATCH, TRG_V, DEC_H, TRG_V);
    }

    // ---- in-place log_softmax over vocab ----
    log_softmax_rows<<<(T_LEN - 1) * BATCH, 256, 0, stream>>>(out + (size_t)BATCH * TRG_V, TRG_V);
}

// Round 6
// 12178.182 us; speedup vs baseline: 2.4807x; 2.1856x over previous
//
#include <hip/hip_runtime.h>
#include <hip/hip_bf16.h>

#define S_LEN 50
#define T_LEN 50
#define BATCH 128
#define EMB 300
#define ENC_H 512
#define DEC_H 1024
#define TRG_V 23262
#define DEC_IN (DEC_H + EMB)      // 1324
#define KCAT (DEC_IN + DEC_H)     // 2348

static inline int cdiv(int a, int b) { return (a + b - 1) / b; }

__device__ __forceinline__ float sigm(float x) { return 1.f / (1.f + expf(-x)); }

typedef __attribute__((ext_vector_type(8))) short bf16x8;
typedef __attribute__((ext_vector_type(4))) float f32x4;

__device__ __forceinline__ void gload_lds16(const void* g, void* l) {
    __builtin_amdgcn_global_load_lds((const __attribute__((address_space(1))) int*)g,
                                     (__attribute__((address_space(3))) int*)l, 16, 0, 0);
}

// ---------------- MFMA bf16 GEMM (generator): C = A @ W^T + bias ----------------
__global__ __launch_bounds__(256)
void gemm_mfma_bf16(const __hip_bfloat16* __restrict__ A, const __hip_bfloat16* __restrict__ W,
                    const float* __restrict__ bias, float* __restrict__ C,
                    int M, int N, int K, int ldc)
{
    __shared__ short As[128 * 32];
    __shared__ short Bs[128 * 32];
    const int tid  = threadIdx.x;
    const int wave = tid >> 6;
    const int lane = tid & 63;
    const int m0 = blockIdx.y * 128;
    const int n0 = blockIdx.x * 128;
    const int wr = wave >> 1, wc = wave & 1;

    const int srow = lane >> 2;
    const int kgrp = lane & 3;
    const int arow0 = 32 * wave;

    f32x4 acc[4][4] = {};

    for (int k0 = 0; k0 < K; k0 += 32) {
#pragma unroll
        for (int c = 0; c < 2; c++) {
            int row = arow0 + 16 * c + srow;
            gload_lds16(A + (size_t)(m0 + row) * K + k0 + kgrp * 8,
                        &As[(arow0 + 16 * c) * 32]);
        }
#pragma unroll
        for (int c = 0; c < 2; c++) {
            int row = arow0 + 16 * c + srow;
            int gr = n0 + row; if (gr > N - 1) gr = N - 1;
            gload_lds16(W + (size_t)gr * K + k0 + kgrp * 8,
                        &Bs[(arow0 + 16 * c) * 32]);
        }
        __syncthreads();

        bf16x8 a[4], b[4];
#pragma unroll
        for (int mi = 0; mi < 4; mi++)
            a[mi] = *(const bf16x8*)&As[(wr * 64 + mi * 16 + (lane & 15)) * 32 + (lane >> 4) * 8];
#pragma unroll
        for (int ni = 0; ni < 4; ni++)
            b[ni] = *(const bf16x8*)&Bs[(wc * 64 + ni * 16 + (lane & 15)) * 32 + (lane >> 4) * 8];
#pragma unroll
        for (int mi = 0; mi < 4; mi++)
#pragma unroll
            for (int ni = 0; ni < 4; ni++)
                acc[mi][ni] = __builtin_amdgcn_mfma_f32_16x16x32_bf16(a[mi], b[ni], acc[mi][ni], 0, 0, 0);
        __syncthreads();
    }

#pragma unroll
    for (int mi = 0; mi < 4; mi++)
#pragma unroll
        for (int ni = 0; ni < 4; ni++) {
            int col = n0 + wc * 64 + ni * 16 + (lane & 15);
            if (col >= N) continue;
            float bv = bias[col];
#pragma unroll
            for (int r = 0; r < 4; r++) {
                int row = m0 + wr * 64 + mi * 16 + (lane >> 4) * 4 + r;
                C[(size_t)row * ldc + col] = acc[mi][ni][r] + bv;
            }
        }
}

__global__ void cast_f32_bf16(const float* __restrict__ in, __hip_bfloat16* __restrict__ out, size_t n)
{
    size_t i = ((size_t)blockIdx.x * blockDim.x + threadIdx.x) * 4;
    if (i + 3 < n) {
        float4 v = *(const float4*)(in + i);
        out[i + 0] = __float2bfloat16(v.x);
        out[i + 1] = __float2bfloat16(v.y);
        out[i + 2] = __float2bfloat16(v.z);
        out[i + 3] = __float2bfloat16(v.w);
    } else {
        for (; i < n; i++) out[i] = __float2bfloat16(in[i]);
    }
}

// ---------------- generic fp32 GEMM (big, 128x128 tiles): C = A @ W^T (+bias) ----------------
template<int BM, int BN, int BK, int TM, int TN, bool HAS_BIAS>
__global__ __launch_bounds__((BM / TM) * (BN / TN))
void gemm_bt(const float* __restrict__ A, const float* __restrict__ W,
             const float* __restrict__ bias, float* __restrict__ C,
             int M, int N, int K, int ldc)
{
    constexpr int NT  = (BM / TM) * (BN / TN);
    constexpr int NGA = TM / 4;
    constexpr int NGB = TN / 4;
    constexpr int GS  = (BN / TN) * 4;
    constexpr int LPA = BM * BK / 4 / NT;
    constexpr int LPB = BN * BK / 4 / NT;

    __shared__ float As[BK][BM + 4];
    __shared__ float Bs[BK][BN + 4];

    const int tid = threadIdx.x;
    const int tx = tid % (BN / TN);
    const int ty = tid / (BN / TN);
    const int m0 = blockIdx.y * BM;
    const int n0 = blockIdx.x * BN;

    float acc[TM][TN];
#pragma unroll
    for (int i = 0; i < TM; i++)
#pragma unroll
        for (int j = 0; j < TN; j++) acc[i][j] = 0.f;

    for (int k0 = 0; k0 < K; k0 += BK) {
#pragma unroll
        for (int e = 0; e < LPA; e++) {
            int idx = tid + e * NT;
            int r = idx / (BK / 4);
            int c4 = idx % (BK / 4);
            int row = m0 + r; if (row > M - 1) row = M - 1;
            int kk = k0 + c4 * 4;
            float4 v;
            if (kk + 3 < K) {
                v = *(const float4*)(A + (size_t)row * K + kk);
            } else {
                v.x = (kk + 0 < K) ? A[(size_t)row * K + kk + 0] : 0.f;
                v.y = (kk + 1 < K) ? A[(size_t)row * K + kk + 1] : 0.f;
                v.z = (kk + 2 < K) ? A[(size_t)row * K + kk + 2] : 0.f;
                v.w = (kk + 3 < K) ? A[(size_t)row * K + kk + 3] : 0.f;
            }
            As[c4 * 4 + 0][r] = v.x; As[c4 * 4 + 1][r] = v.y;
            As[c4 * 4 + 2][r] = v.z; As[c4 * 4 + 3][r] = v.w;
        }
#pragma unroll
        for (int e = 0; e < LPB; e++) {
            int idx = tid + e * NT;
            int r = idx / (BK / 4);
            int c4 = idx % (BK / 4);
            int row = n0 + r; if (row > N - 1) row = N - 1;
            int kk = k0 + c4 * 4;
            float4 v;
            if (kk + 3 < K) {
                v = *(const float4*)(W + (size_t)row * K + kk);
            } else {
                v.x = (kk + 0 < K) ? W[(size_t)row * K + kk + 0] : 0.f;
                v.y = (kk + 1 < K) ? W[(size_t)row * K + kk + 1] : 0.f;
                v.z = (kk + 2 < K) ? W[(size_t)row * K + kk + 2] : 0.f;
                v.w = (kk + 3 < K) ? W[(size_t)row * K + kk + 3] : 0.f;
            }
            Bs[c4 * 4 + 0][r] = v.x; Bs[c4 * 4 + 1][r] = v.y;
            Bs[c4 * 4 + 2][r] = v.z; Bs[c4 * 4 + 3][r] = v.w;
        }
        __syncthreads();
#pragma unroll
        for (int kk = 0; kk < BK; kk++) {
            float a[TM], b[TN];
#pragma unroll
            for (int g = 0; g < NGA; g++) {
                float4 v = *(const float4*)(&As[kk][ty * TM + g * 4]);
                a[g * 4 + 0] = v.x; a[g * 4 + 1] = v.y; a[g * 4 + 2] = v.z; a[g * 4 + 3] = v.w;
            }
#pragma unroll
            for (int g = 0; g < NGB; g++) {
                float4 v = *(const float4*)(&Bs[kk][tx * 4 + g * GS]);
                b[g * 4 + 0] = v.x; b[g * 4 + 1] = v.y; b[g * 4 + 2] = v.z; b[g * 4 + 3] = v.w;
            }
#pragma unroll
            for (int i = 0; i < TM; i++)
#pragma unroll
                for (int j = 0; j < TN; j++)
                    acc[i][j] = fmaf(a[i], b[j], acc[i][j]);
        }
        __syncthreads();
    }

#pragma unroll
    for (int i = 0; i < TM; i++) {
        int row = m0 + ty * TM + i;
        if (row >= M) continue;
#pragma unroll
        for (int g = 0; g < NGB; g++) {
            int colb = n0 + tx * 4 + g * GS;
#pragma unroll
            for (int j = 0; j < 4; j++) {
                int cc = colb + j;
                if (cc >= N) continue;
                float v = acc[i][g * 4 + j];
                if (HAS_BIAS) v += bias[cc];
                C[(size_t)row * ldc + cc] = v;
            }
        }
    }
}

// ---------------- latency-optimized step GEMM (32x64 tile, BK=32, dbuf prefetch) ----------------
// A: 128 x K, W: N x K (N multiple of 64). EPI: 1 = tanh -> catA (ldc=KCAT)
// 2 = encoder LSTM gates (dual via blockIdx.z), 3 = decoder LSTM gates.
// Interleaved weight rows for EPI 2/3: row 4j+gate = original row gate*units+j.
struct StepArgs {
    const float* bias;
    const float* D0; const float* D1;
    float* cst0; float* cst1;
    float* hst0; float* hst1;
    float* enc_out;
    float* catA;
    float* attn_cat;
    float* cdec;
    __hip_bfloat16* H_bf;
    int t;
};

__device__ __forceinline__ float4 g4k(const float* base, int kk, int K) {
    float4 v = make_float4(0.f, 0.f, 0.f, 0.f);
    if (kk + 3 < K) v = *(const float4*)(base + kk);
    else {
        if (kk     < K) v.x = base[kk];
        if (kk + 1 < K) v.y = base[kk + 1];
        if (kk + 2 < K) v.z = base[kk + 2];
    }
    return v;
}

template<int EPI, bool DUAL>
__global__ __launch_bounds__(256)
void step_gemm(const float* __restrict__ A, const float* __restrict__ W, int K,
               const float* __restrict__ A1, const float* __restrict__ W1,
               StepArgs ea)
{
    __shared__ float As[2][32][36];
    __shared__ float Bs[2][32][68];
    const int tid = threadIdx.x;
    const int tx = tid & 15, ty = tid >> 4;
    const int m0 = blockIdx.y * 32, n0 = blockIdx.x * 64;
    const int dir = DUAL ? blockIdx.z : 0;
    const float* Ap = (DUAL && dir) ? A1 : A;
    const float* Wp = (DUAL && dir) ? W1 : W;

    const int ar = tid >> 3, ac4 = tid & 7;
    const float* abase  = Ap + (size_t)(m0 + ar) * K;
    const float* bbase0 = Wp + (size_t)(n0 + ar) * K;
    const float* bbase1 = bbase0 + (size_t)32 * K;

    float acc[2][4] = {{0.f,0.f,0.f,0.f},{0.f,0.f,0.f,0.f}};
    const int NIT = (K + 31) / 32;

    float4 pa, pb0, pb1;
    {
        int kk = ac4 * 4;
        if (32 <= K) { pa = *(const float4*)(abase + kk); pb0 = *(const float4*)(bbase0 + kk); pb1 = *(const float4*)(bbase1 + kk); }
        else { pa = g4k(abase, kk, K); pb0 = g4k(bbase0, kk, K); pb1 = g4k(bbase1, kk, K); }
    }
    *(float4*)&As[0][ar][ac4 * 4] = pa;
    Bs[0][ac4*4+0][ar]    = pb0.x; Bs[0][ac4*4+1][ar]    = pb0.y;
    Bs[0][ac4*4+2][ar]    = pb0.z; Bs[0][ac4*4+3][ar]    = pb0.w;
    Bs[0][ac4*4+0][ar+32] = pb1.x; Bs[0][ac4*4+1][ar+32] = pb1.y;
    Bs[0][ac4*4+2][ar+32] = pb1.z; Bs[0][ac4*4+3][ar+32] = pb1.w;
    __syncthreads();

    int cur = 0;
    for (int it = 0; it < NIT; ++it) {
        float4 qa, qb0, qb1;
        const bool has = (it + 1 < NIT);
        if (has) {
            int k0 = (it + 1) * 32;
            int kk = k0 + ac4 * 4;
            if (k0 + 32 <= K) { qa = *(const float4*)(abase + kk); qb0 = *(const float4*)(bbase0 + kk); qb1 = *(const float4*)(bbase1 + kk); }
            else { qa = g4k(abase, kk, K); qb0 = g4k(bbase0, kk, K); qb1 = g4k(bbase1, kk, K); }
        }
#pragma unroll
        for (int k4 = 0; k4 < 8; ++k4) {
            float4 a0 = *(const float4*)&As[cur][ty*2+0][k4*4];
            float4 a1 = *(const float4*)&As[cur][ty*2+1][k4*4];
            float4 b0 = *(const float4*)&Bs[cur][k4*4+0][tx*4];
            float4 b1 = *(const float4*)&Bs[cur][k4*4+1][tx*4];
            float4 b2 = *(const float4*)&Bs[cur][k4*4+2][tx*4];
            float4 b3 = *(const float4*)&Bs[cur][k4*4+3][tx*4];
            float av0[4] = {a0.x, a0.y, a0.z, a0.w};
            float av1[4] = {a1.x, a1.y, a1.z, a1.w};
            float4 bq[4] = {b0, b1, b2, b3};
#pragma unroll
            for (int q = 0; q < 4; q++) {
                acc[0][0] = fmaf(av0[q], bq[q].x, acc[0][0]);
                acc[0][1] = fmaf(av0[q], bq[q].y, acc[0][1]);
                acc[0][2] = fmaf(av0[q], bq[q].z, acc[0][2]);
                acc[0][3] = fmaf(av0[q], bq[q].w, acc[0][3]);
                acc[1][0] = fmaf(av1[q], bq[q].x, acc[1][0]);
                acc[1][1] = fmaf(av1[q], bq[q].y, acc[1][1]);
                acc[1][2] = fmaf(av1[q], bq[q].z, acc[1][2]);
                acc[1][3] = fmaf(av1[q], bq[q].w, acc[1][3]);
            }
        }
        if (has) {
            int nb = cur ^ 1;
            *(float4*)&As[nb][ar][ac4 * 4] = qa;
            Bs[nb][ac4*4+0][ar]    = qb0.x; Bs[nb][ac4*4+1][ar]    = qb0.y;
            Bs[nb][ac4*4+2][ar]    = qb0.z; Bs[nb][ac4*4+3][ar]    = qb0.w;
            Bs[nb][ac4*4+0][ar+32] = qb1.x; Bs[nb][ac4*4+1][ar+32] = qb1.y;
            Bs[nb][ac4*4+2][ar+32] = qb1.z; Bs[nb][ac4*4+3][ar+32] = qb1.w;
        }
        __syncthreads();
        cur ^= 1;
    }

    const int cb = n0 + tx * 4;
    if (EPI == 1) {
#pragma unroll
        for (int i = 0; i < 2; i++) {
            int row = m0 + ty * 2 + i;
            float* dst = ea.catA + (size_t)row * KCAT + cb;
            dst[0] = tanhf(acc[i][0]); dst[1] = tanhf(acc[i][1]);
            dst[2] = tanhf(acc[i][2]); dst[3] = tanhf(acc[i][3]);
        }
    } else if (EPI == 2) {
        const float* D = dir ? ea.D1 : ea.D0;
        float* cst = dir ? ea.cst1 : ea.cst0;
        float* hst = dir ? ea.hst1 : ea.hst0;
        int j = cb >> 2;
        int s_out = dir ? (S_LEN - 1 - ea.t) : ea.t;
#pragma unroll
        for (int i = 0; i < 2; i++) {
            int b = m0 + ty * 2 + i;
            float4 d = *(const float4*)(D + (size_t)b * (4 * ENC_H) + cb);
            float gi = acc[i][0] + d.x, gf = acc[i][1] + d.y;
            float gg = acc[i][2] + d.z, go = acc[i][3] + d.w;
            float c2 = sigm(gf) * cst[b * ENC_H + j] + sigm(gi) * tanhf(gg);
            float h2 = sigm(go) * tanhf(c2);
            cst[b * ENC_H + j] = c2;
            hst[b * ENC_H + j] = h2;
            ea.enc_out[((size_t)s_out * BATCH + b) * DEC_H + dir * ENC_H + j] = h2;
        }
    } else if (EPI == 3) {
        int j = cb >> 2;
        float4 bz = *(const float4*)(ea.bias + cb);
#pragma unroll
        for (int i = 0; i < 2; i++) {
            int b = m0 + ty * 2 + i;
            float gi = acc[i][0] + bz.x, gf = acc[i][1] + bz.y;
            float gg = acc[i][2] + bz.z, go = acc[i][3] + bz.w;
            float c2 = sigm(gf) * ea.cdec[b * DEC_H + j] + sigm(gi) * tanhf(gg);
            float h2 = sigm(go) * tanhf(c2);
            ea.cdec[b * DEC_H + j] = c2;
            ea.H_bf[(size_t)ea.t * BATCH * DEC_H + b * DEC_H + j] = __float2bfloat16(h2);
            ea.attn_cat[(size_t)b * 2 * DEC_H + DEC_H + j] = h2;
        }
    }
}

// ---------------- small kernels ----------------
__global__ void zero_f32(float* p, size_t n) {
    size_t i = (size_t)blockIdx.x * blockDim.x + threadIdx.x;
    if (i < n) p[i] = 0.f;
}

__global__ void gather_rows(const int* __restrict__ ids, const float* __restrict__ E,
                            float* __restrict__ out, int nrows, int width)
{
    size_t i = (size_t)blockIdx.x * blockDim.x + threadIdx.x;
    size_t total = (size_t)nrows * width;
    if (i >= total) return;
    int r = (int)(i / width);
    int e = (int)(i % width);
    out[i] = E[(size_t)ids[r] * width + e];
}

// interleave gate rows: dst row 4j+gate <- src row gate*units+j
__global__ void interleave_rows(const float* __restrict__ src, float* __restrict__ dst,
                                int units, int kdim)
{
    size_t i = (size_t)blockIdx.x * blockDim.x + threadIdx.x;
    size_t total = (size_t)4 * units * kdim;
    if (i >= total) return;
    int ir = (int)(i / kdim), k = (int)(i % kdim);
    int gate = ir & 3, j = ir >> 2;
    dst[i] = src[(size_t)(gate * units + j) * kdim + k];
}

__global__ void interleave_vec(const float* __restrict__ src, float* __restrict__ dst, int units)
{
    int i = blockIdx.x * blockDim.x + threadIdx.x;
    if (i >= 4 * units) return;
    int gate = i & 3, j = i >> 2;
    dst[i] = src[gate * units + j];
}

__global__ void build_wcat_int(const float* __restrict__ Wih, const float* __restrict__ Whh,
                               float* __restrict__ dst)
{
    size_t i = (size_t)blockIdx.x * blockDim.x + threadIdx.x;
    if (i >= (size_t)4 * DEC_H * KCAT) return;
    int ir = (int)(i / KCAT), k = (int)(i % KCAT);
    int gate = ir & 3, j = ir >> 2;
    int r = gate * DEC_H + j;
    dst[i] = (k < DEC_IN) ? Wih[(size_t)r * DEC_IN + k] : Whh[(size_t)r * DEC_H + (k - DEC_IN)];
}

__global__ void transpose_sq(const float* __restrict__ src, float* __restrict__ dst, int n)
{
    int i = blockIdx.x * blockDim.x + threadIdx.x;
    if (i >= n * n) return;
    int r = i / n, c = i % n;
    dst[(size_t)r * n + c] = src[(size_t)c * n + r];
}

// decoder init: interleave h0/c0; attn t=0 fills catA
__global__ void dec_init2(const float* __restrict__ hF, const float* __restrict__ cF,
                          const float* __restrict__ hR, const float* __restrict__ cR,
                          float* __restrict__ attn_cat, float* __restrict__ cdec)
{
    int idx = blockIdx.x * blockDim.x + threadIdx.x;
    if (idx >= BATCH * DEC_H) return;
    int b = idx / DEC_H, j = idx % DEC_H;
    int half = j >> 1;
    float h = (j & 1) ? hR[b * ENC_H + half] : hF[b * ENC_H + half];
    float c = (j & 1) ? cR[b * ENC_H + half] : cF[b * ENC_H + half];
    attn_cat[(size_t)b * 2 * DEC_H + DEC_H + j] = h;
    cdec[idx] = c;
}

// attention (uses hoisted encP); also stages x_emb_t and h_t into catA
__global__ __launch_bounds__(256)
void attn_fused(const float* __restrict__ encP, const float* __restrict__ enc_out,
                const float* __restrict__ trg_emb, float* __restrict__ attn_cat,
                float* __restrict__ catA, int t)
{
    int b = blockIdx.x, tid = threadIdx.x;
    __shared__ float hv[DEC_H];
    __shared__ float sc[S_LEN];
    for (int d = tid; d < DEC_H; d += 256) hv[d] = attn_cat[(size_t)b * 2 * DEC_H + DEC_H + d];
    __syncthreads();
    for (int e = tid; e < EMB; e += 256)
        catA[(size_t)b * KCAT + DEC_H + e] = trg_emb[((size_t)t * BATCH + b) * EMB + e];
    for (int d = tid; d < DEC_H; d += 256)
        catA[(size_t)b * KCAT + DEC_IN + d] = hv[d];
    int wave = tid >> 6, lane = tid & 63;
    for (int s = wave; s < S_LEN; s += 4) {
        const float* e = encP + ((size_t)s * BATCH + b) * DEC_H;
        float p = 0.f;
        for (int d = lane; d < DEC_H; d += 64) p = fmaf(e[d], hv[d], p);
        for (int off = 32; off; off >>= 1) p += __shfl_down(p, off);
        if (lane == 0) sc[s] = p;
    }
    __syncthreads();
    if (tid < 64) {
        float x = (tid < S_LEN) ? sc[tid] : -1e30f;
        float m = x;
        for (int off = 32; off; off >>= 1) m = fmaxf(m, __shfl_xor(m, off));
        float ex = (tid < S_LEN) ? expf(x - m) : 0.f;
        float ssum = ex;
        for (int off = 32; off; off >>= 1) ssum += __shfl_xor(ssum, off);
        if (tid < S_LEN) sc[tid] = ex / ssum;
    }
    __syncthreads();
    for (int d = tid; d < DEC_H; d += 256) {
        float a = 0.f;
#pragma unroll 5
        for (int s = 0; s < S_LEN; s++)
            a = fmaf(sc[s], enc_out[((size_t)s * BATCH + b) * DEC_H + d], a);
        attn_cat[(size_t)b * 2 * DEC_H + d] = a;
    }
}

__global__ __launch_bounds__(256)
void log_softmax_rows(float* __restrict__ X, int V)
{
    int row = blockIdx.x;
    float* x = X + (size_t)row * V;
    int tid = threadIdx.x;
    __shared__ float redm[4], reds[4];
    float m = -1e30f;
    for (int i = tid; i < V; i += 256) m = fmaxf(m, x[i]);
    for (int off = 32; off; off >>= 1) m = fmaxf(m, __shfl_xor(m, off));
    if ((tid & 63) == 0) redm[tid >> 6] = m;
    __syncthreads();
    m = fmaxf(fmaxf(redm[0], redm[1]), fmaxf(redm[2], redm[3]));
    float s = 0.f;
    for (int i = tid; i < V; i += 256) s += expf(x[i] - m);
    for (int off = 32; off; off >>= 1) s += __shfl_xor(s, off);
    if ((tid & 63) == 0) reds[tid >> 6] = s;
    __syncthreads();
    s = reds[0] + reds[1] + reds[2] + reds[3];
    float lg = m + logf(s);
    for (int i = tid; i < V; i += 256) x[i] -= lg;
}

// ---------------- big GEMM launchers ----------------
static void launch_gemm_big_bias(const float* A, const float* W, const float* bias, float* C,
                                 int M, int N, int K, int ldc, hipStream_t s)
{
    dim3 g(cdiv(N, 128), cdiv(M, 128), 1);
    gemm_bt<128, 128, 16, 8, 8, true><<<g, 256, 0, s>>>(A, W, bias, C, M, N, K, ldc);
}
static void launch_gemm_big(const float* A, const float* W, float* C,
                            int M, int N, int K, int ldc, hipStream_t s)
{
    dim3 g(cdiv(N, 128), cdiv(M, 128), 1);
    gemm_bt<128, 128, 16, 8, 8, false><<<g, 256, 0, s>>>(A, W, nullptr, C, M, N, K, ldc);
}

extern "C" void kernel_launch(void* const* d_in, const int* in_sizes, int n_in,
                              void* d_out, int out_size, void* d_ws, size_t ws_size,
                              hipStream_t stream)
{
    const int*   src   = (const int*)d_in[0];
    const int*   trg   = (const int*)d_in[1];
    const float* EEMBp = (const float*)d_in[2];
    const float* eWihF = (const float*)d_in[3];
    const float* eWhhF = (const float*)d_in[4];
    const float* ebF   = (const float*)d_in[5];
    const float* eWihR = (const float*)d_in[6];
    const float* eWhhR = (const float*)d_in[7];
    const float* ebR   = (const float*)d_in[8];
    const float* aWi   = (const float*)d_in[9];
    const float* aWo   = (const float*)d_in[10];
    const float* dWih  = (const float*)d_in[11];
    const float* dWhh  = (const float*)d_in[12];
    const float* db    = (const float*)d_in[13];
    const float* DEMBp = (const float*)d_in[14];
    const float* gW    = (const float*)d_in[15];
    const float* gb    = (const float*)d_in[16];
    float* out = (float*)d_out;
    float* ws  = (float*)d_ws;

    size_t off = 0;
    auto alloc = [&](size_t n) { float* p = ws + off; off += n; return p; };

    float* Gf      = alloc((size_t)S_LEN * BATCH * 4 * ENC_H);   // interleaved; gWb alias later
    float* Gr      = alloc((size_t)S_LEN * BATCH * 4 * ENC_H);   // interleaved; encP alias later
    float* emb_src = alloc((size_t)S_LEN * BATCH * EMB);
    float* enc_out = alloc((size_t)S_LEN * BATCH * DEC_H);
    float* hF2     = alloc((size_t)2 * BATCH * ENC_H);           // ping-pong
    float* hR2     = alloc((size_t)2 * BATCH * ENC_H);
    float* cF      = alloc(BATCH * ENC_H);
    float* cR      = alloc(BATCH * ENC_H);
    float* trg_emb = alloc((size_t)(T_LEN - 1) * BATCH * EMB);
    float* wihF_i  = alloc((size_t)4 * ENC_H * EMB);
    float* wihR_i  = alloc((size_t)4 * ENC_H * EMB);
    float* whhF_i  = alloc((size_t)4 * ENC_H * ENC_H);
    float* whhR_i  = alloc((size_t)4 * ENC_H * ENC_H);
    float* ebF_i   = alloc(4 * ENC_H);
    float* ebR_i   = alloc(4 * ENC_H);
    float* wcat_i  = alloc((size_t)4 * DEC_H * KCAT);
    float* db_i    = alloc(4 * DEC_H);
    float* aWiT    = alloc((size_t)DEC_H * DEC_H);
    float* cdec    = alloc(BATCH * DEC_H);
    float* attn_cat= alloc((size_t)BATCH * 2 * DEC_H);           // [s_tilde | h]
    float* catA    = alloc((size_t)BATCH * KCAT);                // [c_t | emb | h]
    __hip_bfloat16* H_bf = (__hip_bfloat16*)alloc((size_t)(T_LEN - 1) * BATCH * DEC_H / 2);
    __hip_bfloat16* gWb  = (__hip_bfloat16*)Gf;                  // alias (Gf dead after enc loop)
    float* encP = Gr;                                            // alias (Gr dead after enc loop)

    const int HS = BATCH * ENC_H;  // 65536

    // ---- zero: first output slice + h/c states (hF2..cR contiguous = 6*HS) ----
    zero_f32<<<cdiv(BATCH * TRG_V, 256), 256, 0, stream>>>(out, (size_t)BATCH * TRG_V);
    zero_f32<<<cdiv(6 * HS, 256), 256, 0, stream>>>(hF2, (size_t)6 * HS);

    // ---- embeddings ----
    gather_rows<<<cdiv(S_LEN * BATCH * EMB, 256), 256, 0, stream>>>(src, EEMBp, emb_src, S_LEN * BATCH, EMB);
    gather_rows<<<cdiv((T_LEN - 1) * BATCH * EMB, 256), 256, 0, stream>>>(trg, DEMBp, trg_emb, (T_LEN - 1) * BATCH, EMB);

    // ---- interleaved weights/biases + aWi transpose ----
    interleave_rows<<<cdiv(4 * ENC_H * EMB, 256), 256, 0, stream>>>(eWihF, wihF_i, ENC_H, EMB);
    interleave_rows<<<cdiv(4 * ENC_H * EMB, 256), 256, 0, stream>>>(eWihR, wihR_i, ENC_H, EMB);
    interleave_rows<<<cdiv(4 * ENC_H * ENC_H, 256), 256, 0, stream>>>(eWhhF, whhF_i, ENC_H, ENC_H);
    interleave_rows<<<cdiv(4 * ENC_H * ENC_H, 256), 256, 0, stream>>>(eWhhR, whhR_i, ENC_H, ENC_H);
    interleave_vec<<<cdiv(4 * ENC_H, 256), 256, 0, stream>>>(ebF, ebF_i, ENC_H);
    interleave_vec<<<cdiv(4 * ENC_H, 256), 256, 0, stream>>>(ebR, ebR_i, ENC_H);
    build_wcat_int<<<cdiv(4 * DEC_H * KCAT, 256), 256, 0, stream>>>(dWih, dWhh, wcat_i);
    interleave_vec<<<cdiv(4 * DEC_H, 256), 256, 0, stream>>>(db, db_i, DEC_H);
    transpose_sq<<<cdiv(DEC_H * DEC_H, 256), 256, 0, stream>>>(aWi, aWiT, DEC_H);

    // ---- encoder input GEMMs (interleaved gate cols, bias folded) ----
    launch_gemm_big_bias(emb_src, wihF_i, ebF_i, Gf, S_LEN * BATCH, 4 * ENC_H, EMB, 4 * ENC_H, stream);
    launch_gemm_big_bias(emb_src, wihR_i, ebR_i, Gr, S_LEN * BATCH, 4 * ENC_H, EMB, 4 * ENC_H, stream);

    // ---- encoder recurrence: 1 launch/step, gates fused in epilogue ----
    for (int t = 0; t < S_LEN; t++) {
        StepArgs ea{};
        ea.D0 = Gf + (size_t)t * BATCH * 4 * ENC_H;
        ea.D1 = Gr + (size_t)(S_LEN - 1 - t) * BATCH * 4 * ENC_H;
        ea.cst0 = cF; ea.cst1 = cR;
        ea.hst0 = hF2 + ((t + 1) & 1) * HS;
        ea.hst1 = hR2 + ((t + 1) & 1) * HS;
        ea.enc_out = enc_out; ea.t = t;
        dim3 g(4 * ENC_H / 64, BATCH / 32, 2);
        step_gemm<2, true><<<g, 256, 0, stream>>>(hF2 + (t & 1) * HS, whhF_i, ENC_H,
                                                  hR2 + (t & 1) * HS, whhR_i, ea);
    }

    // ---- hoisted: encP = enc_out @ aWi  (for per-step scores) ----
    launch_gemm_big(enc_out, aWiT, encP, S_LEN * BATCH, DEC_H, DEC_H, DEC_H, stream);

    // ---- cast generator weights into Gf's dead space ----
    cast_f32_bf16<<<cdiv((int)((size_t)TRG_V * DEC_H / 4), 256), 256, 0, stream>>>(gW, gWb, (size_t)TRG_V * DEC_H);

    // ---- decoder init (h0/c0 interleave; attn t=0 fills catA) ----
    dec_init2<<<cdiv(BATCH * DEC_H, 256), 256, 0, stream>>>(hF2, cF, hR2, cR, attn_cat, cdec);

    // ---- decoder recurrence: 3 launches/step ----
    for (int t = 0; t < T_LEN - 1; t++) {
        attn_fused<<<BATCH, 256, 0, stream>>>(encP, enc_out, trg_emb, attn_cat, catA, t);
        {
            StepArgs ea{}; ea.catA = catA;
            dim3 g(DEC_H / 64, BATCH / 32, 1);
            step_gemm<1, false><<<g, 256, 0, stream>>>(attn_cat, aWo, 2 * DEC_H, nullptr, nullptr, ea);
        }
        {
            StepArgs ea{};
            ea.bias = db_i; ea.cdec = cdec; ea.attn_cat = attn_cat; ea.H_bf = H_bf; ea.t = t;
            dim3 g(4 * DEC_H / 64, BATCH / 32, 1);
            step_gemm<3, false><<<g, 256, 0, stream>>>(catA, wcat_i, KCAT, nullptr, nullptr, ea);
        }
    }

    // ---- generator: MFMA bf16 GEMM ----
    {
        dim3 g(cdiv(TRG_V, 128), cdiv((T_LEN - 1) * BATCH, 128), 1);
        gemm_mfma_bf16<<<g, 256, 0, stream>>>(H_bf, gWb, gb, out + (size_t)BATCH * TRG_V,
                                              (T_LEN - 1) * BATCH, TRG_V, DEC_H, TRG_V);
    }

    // ---- in-place log_softmax over vocab ----
    log_softmax_rows<<<(T_LEN - 1) * BATCH, 256, 0, stream>>>(out + (size_t)BATCH * TRG_V, TRG_V);
}